// Round 12
// baseline (114.717 us; speedup 1.0000x reference)
//
#include <hip/hip_runtime.h>

// ScaledDotProductAttention B=8, L=2048, D=64, fp32 in/out.
//
// Two-launch scheme (ws >= 8 MB):
//  1) prepass: K -> fp16 copy (K16), V -> fp16 transposed (VT16) in d_ws.
//  2) attn_hi: grid 256 (8 batch x 32 qblocks of 64 queries), 1024 threads =
//     16 waves/block -> 4 waves/SIMD (50% occupancy; R11 measured the 2-wave
//     version at 18% occ / 70% stall -- TLP is the missing lever).
//     Wave (qw,kw): qw=wave>>3 owns queries [qw*32,+32), kw=wave&7 owns keys
//     [kw*256,+256) = 8 tiles of 32. No K double-buffer (TLP hides latency;
//     keeps VGPR ~120 < 128 cap for 4 waves/SIMD -- R11's 128-cap spilled).
//     Hot loop: ZERO LDS, ZERO cross-lane (R9/R10-verified layout algebra):
//       - S^T = K*Q^T via mfma_f32_16x16x32_f16; C-layout: lane holds
//         S^T[key=quad*4+r][q=qs*16+l15].
//       - p = exp2(s) (0.125*log2e folded into Q); packed half4 IS the
//         B-frag of mfma_f32_16x16x16f16 -> PV straight from registers.
//       - PV: O^T += VT16 half4 A-frags x P^T; float4-per-query store.
//     Epilogue: 4 rounds (qw x qs) over 36 KB LDS; 8-wave combine per round.
// Fallback: proven R3 kernel if ws too small.

#define B_ 8
#define L_ 2048
#define D_ 64
#define NT 256

typedef _Float16 half8_t __attribute__((ext_vector_type(8)));
typedef _Float16 half4_t __attribute__((ext_vector_type(4)));
typedef float f32x4 __attribute__((ext_vector_type(4)));

#define SCALE_LOG2E 0.1803368801111244f   // 0.125 * log2(e)

// ---------------------------------------------------------------- prepass --
// blocks 0..511: K cast; 512..767: V transpose.
__global__ __launch_bounds__(NT) void prepass(
    const float* __restrict__ K, const float* __restrict__ V,
    _Float16* __restrict__ K16, _Float16* __restrict__ VT16)
{
    const int blk = blockIdx.x;
    const int t = threadIdx.x;
    if (blk < 512) {
        const int i = blk * NT + t;                  // half8 index, 131072 total
        const float4* s4 = (const float4*)K;
        const float4 a = s4[2 * i], b = s4[2 * i + 1];
        half8_t w;
        w[0] = (_Float16)a.x; w[1] = (_Float16)a.y;
        w[2] = (_Float16)a.z; w[3] = (_Float16)a.w;
        w[4] = (_Float16)b.x; w[5] = (_Float16)b.y;
        w[6] = (_Float16)b.z; w[7] = (_Float16)b.w;
        ((half8_t*)K16)[i] = w;
    } else {
        __shared__ __align__(16) _Float16 Lt[64 * 72];   // [dim][key] tile
        const int vblk = blk - 512;
        const int bb = vblk >> 5;            // batch
        const int kt = vblk & 31;            // 64-key tile
        const int r  = t >> 2;               // key row 0..63
        const int ch = t & 3;                // 16-dim chunk
        const float* vrow = V + ((size_t)bb * L_ + kt * 64 + r) * D_ + ch * 16;
        #pragma unroll
        for (int i = 0; i < 4; ++i) {
            const float4 f = ((const float4*)vrow)[i];
            const int d0 = ch * 16 + i * 4;
            Lt[(d0 + 0) * 72 + r] = (_Float16)f.x;
            Lt[(d0 + 1) * 72 + r] = (_Float16)f.y;
            Lt[(d0 + 2) * 72 + r] = (_Float16)f.z;
            Lt[(d0 + 3) * 72 + r] = (_Float16)f.w;
        }
        __syncthreads();
        const int d  = t >> 2;               // dim row 0..63
        const int c2 = t & 3;                // 16-key chunk
        const half8_t w0 = *(const half8_t*)&Lt[d * 72 + c2 * 16];
        const half8_t w1 = *(const half8_t*)&Lt[d * 72 + c2 * 16 + 8];
        _Float16* orow = VT16 + ((size_t)bb * D_ + d) * L_ + kt * 64 + c2 * 16;
        *(half8_t*)orow = w0;
        *(half8_t*)(orow + 8) = w1;
    }
}

// -------------------------------------------------------------- main body --
__global__ __launch_bounds__(1024) void attn_hi(
    const float* __restrict__ Q,
    const _Float16* __restrict__ K16,
    const _Float16* __restrict__ VT16,
    float* __restrict__ O)
{
    __shared__ float Ored[512 * 17];                     // 34816 B (epilogue only)
    __shared__ float Lred[512];                          // 2 KB

    const int t    = threadIdx.x;
    const int wave = t >> 6;                   // 0..15
    const int lane = t & 63;
    const int quad = lane >> 4;
    const int l15  = lane & 15;
    const int qw   = wave >> 3;                // query-half owner (0,1)
    const int kw   = wave & 7;                 // key-range owner (0..7)

    const int b   = blockIdx.x & 7;            // batch <-> XCD affinity
    const int qbi = blockIdx.x >> 3;           // query block 0..31
    const int qb  = qbi * 64 + qw * 32;        // this wave's first query
    const int key0 = kw * 256;                 // this wave's 256-key range

    const _Float16* Kb = K16 + (size_t)b * L_ * D_;
    const _Float16* Vb = VT16 + (size_t)b * D_ * L_;

    // ---- Q B-frags from fp32, pre-scaled by 0.125*log2(e) ----
    half8_t bq[2][2];
    #pragma unroll
    for (int qs = 0; qs < 2; ++qs) {
        const float* qp = Q + ((size_t)b * L_ + qb + qs * 16 + l15) * D_ + quad * 8;
        #pragma unroll
        for (int c = 0; c < 2; ++c) {
            const float4 f0 = *(const float4*)(qp + c * 32);
            const float4 f1 = *(const float4*)(qp + c * 32 + 4);
            bq[qs][c][0] = (_Float16)(f0.x * SCALE_LOG2E);
            bq[qs][c][1] = (_Float16)(f0.y * SCALE_LOG2E);
            bq[qs][c][2] = (_Float16)(f0.z * SCALE_LOG2E);
            bq[qs][c][3] = (_Float16)(f0.w * SCALE_LOG2E);
            bq[qs][c][4] = (_Float16)(f1.x * SCALE_LOG2E);
            bq[qs][c][5] = (_Float16)(f1.y * SCALE_LOG2E);
            bq[qs][c][6] = (_Float16)(f1.z * SCALE_LOG2E);
            bq[qs][c][7] = (_Float16)(f1.w * SCALE_LOG2E);
        }
    }

    f32x4 ofr[2][4];
    #pragma unroll
    for (int qs = 0; qs < 2; ++qs)
        #pragma unroll
        for (int d = 0; d < 4; ++d)
            ofr[qs][d] = (f32x4){0.f, 0.f, 0.f, 0.f};
    float lacc[2] = {0.f, 0.f};

    // ---- hot loop: 8 tiles of 32 keys; TLP (4 waves/SIMD) hides latency ----
    for (int it = 0; it < 8; ++it) {
        const int kb = key0 + it * 32;

        // all loads for this tile issued together
        half8_t bk[2][2];
        #pragma unroll
        for (int s = 0; s < 2; ++s)
            #pragma unroll
            for (int c = 0; c < 2; ++c)
                bk[s][c] = *(const half8_t*)&Kb[(size_t)(kb + s * 16 + l15) * D_ + c * 32 + quad * 8];
        half4_t av[4][2];
        #pragma unroll
        for (int d = 0; d < 4; ++d)
            #pragma unroll
            for (int ks = 0; ks < 2; ++ks)
                av[d][ks] = *(const half4_t*)&Vb[(size_t)(d * 16 + l15) * L_ + kb + ks * 16 + quad * 4];

        // QK^T (transposed): S^T = K * Q^T
        f32x4 sc[2][2];
        #pragma unroll
        for (int ks = 0; ks < 2; ++ks)
            #pragma unroll
            for (int qs = 0; qs < 2; ++qs) {
                f32x4 acc = (f32x4){0.f, 0.f, 0.f, 0.f};
                acc = __builtin_amdgcn_mfma_f32_16x16x32_f16(bk[ks][0], bq[qs][0], acc, 0, 0, 0);
                acc = __builtin_amdgcn_mfma_f32_16x16x32_f16(bk[ks][1], bq[qs][1], acc, 0, 0, 0);
                sc[ks][qs] = acc;
            }

        // softmax numerator: p = 2^s; pack to PV B-frags
        half4_t pb[2][2];
        #pragma unroll
        for (int ks = 0; ks < 2; ++ks)
            #pragma unroll
            for (int qs = 0; qs < 2; ++qs) {
                const float p0 = __builtin_exp2f(sc[ks][qs][0]);
                const float p1 = __builtin_exp2f(sc[ks][qs][1]);
                const float p2 = __builtin_exp2f(sc[ks][qs][2]);
                const float p3 = __builtin_exp2f(sc[ks][qs][3]);
                lacc[qs] += (p0 + p1) + (p2 + p3);
                half4_t pv;
                pv[0] = (_Float16)p0; pv[1] = (_Float16)p1;
                pv[2] = (_Float16)p2; pv[3] = (_Float16)p3;
                pb[ks][qs] = pv;
            }

        // PV: O^T += V^T x P^T  (K=16 MFMA, B-frag straight from registers)
        #pragma unroll
        for (int qs = 0; qs < 2; ++qs)
            #pragma unroll
            for (int d = 0; d < 4; ++d)
                #pragma unroll
                for (int ks = 0; ks < 2; ++ks)
                    ofr[qs][d] = __builtin_amdgcn_mfma_f32_16x16x16f16(av[d][ks], pb[ks][qs], ofr[qs][d], 0, 0, 0);
    }

    // ---- l: reduce over quads ----
    #pragma unroll
    for (int qs = 0; qs < 2; ++qs) {
        float v = lacc[qs];
        v += __shfl_xor(v, 16, 64);
        v += __shfl_xor(v, 32, 64);
        lacc[qs] = v;
    }
    if (quad == 0) {
        Lred[wave * 32 + l15] = lacc[0];
        Lred[wave * 32 + 16 + l15] = lacc[1];
    }

    // ---- cross-wave combine: 4 rounds (qw-group x qs) over shared buffer ----
    #pragma unroll
    for (int p = 0; p < 2; ++p)
        #pragma unroll
        for (int qs = 0; qs < 2; ++qs) {
            __syncthreads();   // prior round's reads done (also covers Lred)
            if (qw == p) {
                #pragma unroll
                for (int d = 0; d < 4; ++d)
                    #pragma unroll
                    for (int r = 0; r < 4; ++r)
                        Ored[(kw * 64 + lane) * 17 + d * 4 + r] = ofr[qs][d][r];
            }
            __syncthreads();
            if (qw == p && kw < 4) {
                float lt = 0.f;
                #pragma unroll
                for (int k2 = 0; k2 < 8; ++k2)
                    lt += Lred[(p * 8 + k2) * 32 + qs * 16 + l15];
                const float inv = 1.0f / lt;
                f32x4 osum = (f32x4){0.f, 0.f, 0.f, 0.f};
                #pragma unroll
                for (int w2 = 0; w2 < 8; ++w2) {
                    const float* src = &Ored[(w2 * 64 + lane) * 17 + kw * 4];
                    osum[0] += src[0]; osum[1] += src[1];
                    osum[2] += src[2]; osum[3] += src[3];
                }
                float4 outv;
                outv.x = osum[0] * inv; outv.y = osum[1] * inv;
                outv.z = osum[2] * inv; outv.w = osum[3] * inv;
                // query = qb + qs*16 + l15 ; dims = kw*16 + quad*4 .. +4
                *(float4*)&O[((size_t)b * L_ + qb + qs * 16 + l15) * D_ + kw * 16 + quad * 4] = outv;
            }
        }
}

// ------------------------------------------------- fallback (R3, no ws) --
#define KS 72
__global__ __launch_bounds__(NT) void attn_mfma_f16(
    const float* __restrict__ Q, const float* __restrict__ K,
    const float* __restrict__ V, float* __restrict__ O)
{
    __shared__ __align__(16) _Float16 Kt[64 * KS];
    __shared__ __align__(16) _Float16 Vt[D_ * KS];
    __shared__ __align__(16) _Float16 Pt[4][16 * KS];

    const int t = threadIdx.x;
    const int wave = t >> 6, lane = t & 63, quad = lane >> 4, l15 = lane & 15;
    const int bpb = L_ / 64;
    const int b = blockIdx.x / bpb;
    const int qb = (blockIdx.x % bpb) * 64 + wave * 16;
    const size_t boff = (size_t)b * L_ * D_;

    half8_t aq[2];
    {
        const float* qp = Q + boff + (size_t)(qb + l15) * D_ + quad * 8;
        #pragma unroll
        for (int c = 0; c < 2; ++c) {
            const float4* p4 = (const float4*)(qp + c * 32);
            const float4 f0 = p4[0], f1 = p4[1];
            aq[c][0] = (_Float16)f0.x; aq[c][1] = (_Float16)f0.y;
            aq[c][2] = (_Float16)f0.z; aq[c][3] = (_Float16)f0.w;
            aq[c][4] = (_Float16)f1.x; aq[c][5] = (_Float16)f1.y;
            aq[c][6] = (_Float16)f1.z; aq[c][7] = (_Float16)f1.w;
        }
    }
    f32x4 ofr[4];
    #pragma unroll
    for (int d = 0; d < 4; ++d) ofr[d] = (f32x4){0.f, 0.f, 0.f, 0.f};
    float lacc[4] = {0.f, 0.f, 0.f, 0.f};
    const int skey = t & 63, sdg = t >> 6;
    _Float16* Pw = &Pt[wave][0];

    for (int kt = 0; kt < L_ / 64; ++kt) {
        __syncthreads();
        {
            const float4* kg4 = (const float4*)(K + boff + (size_t)(kt * 64 + skey) * D_ + sdg * 16);
            const float4 f0 = kg4[0], f1 = kg4[1], f2 = kg4[2], f3 = kg4[3];
            half8_t w0, w1;
            w0[0] = (_Float16)f0.x; w0[1] = (_Float16)f0.y;
            w0[2] = (_Float16)f0.z; w0[3] = (_Float16)f0.w;
            w0[4] = (_Float16)f1.x; w0[5] = (_Float16)f1.y;
            w0[6] = (_Float16)f1.z; w0[7] = (_Float16)f1.w;
            w1[0] = (_Float16)f2.x; w1[1] = (_Float16)f2.y;
            w1[2] = (_Float16)f2.z; w1[3] = (_Float16)f2.w;
            w1[4] = (_Float16)f3.x; w1[5] = (_Float16)f3.y;
            w1[6] = (_Float16)f3.z; w1[7] = (_Float16)f3.w;
            *(half8_t*)&Kt[skey * KS + sdg * 16] = w0;
            *(half8_t*)&Kt[skey * KS + sdg * 16 + 8] = w1;
        }
        {
            const float4* vg4 = (const float4*)(V + boff + (size_t)(kt * 64 + skey) * D_ + sdg * 16);
            #pragma unroll
            for (int i = 0; i < 4; ++i) {
                const float4 f = vg4[i];
                const int d0 = sdg * 16 + i * 4;
                Vt[(d0 + 0) * KS + skey] = (_Float16)f.x;
                Vt[(d0 + 1) * KS + skey] = (_Float16)f.y;
                Vt[(d0 + 2) * KS + skey] = (_Float16)f.z;
                Vt[(d0 + 3) * KS + skey] = (_Float16)f.w;
            }
        }
        __syncthreads();
        #pragma unroll
        for (int s = 0; s < 4; ++s) {
            const half8_t bk0 = *(const half8_t*)&Kt[(s * 16 + l15) * KS + quad * 8];
            const half8_t bk1 = *(const half8_t*)&Kt[(s * 16 + l15) * KS + 32 + quad * 8];
            f32x4 sc = (f32x4){0.f, 0.f, 0.f, 0.f};
            sc = __builtin_amdgcn_mfma_f32_16x16x32_f16(aq[0], bk0, sc, 0, 0, 0);
            sc = __builtin_amdgcn_mfma_f32_16x16x32_f16(aq[1], bk1, sc, 0, 0, 0);
            #pragma unroll
            for (int r = 0; r < 4; ++r) {
                const float p = __expf(sc[r] * 0.125f);
                lacc[r] += p;
                Pw[(quad * 4 + r) * KS + s * 16 + l15] = (_Float16)p;
            }
        }
        __syncthreads();
        #pragma unroll
        for (int c = 0; c < 2; ++c) {
            const half8_t ap = *(const half8_t*)&Pw[l15 * KS + c * 32 + quad * 8];
            #pragma unroll
            for (int d = 0; d < 4; ++d) {
                const half8_t bv = *(const half8_t*)&Vt[(d * 16 + l15) * KS + c * 32 + quad * 8];
                ofr[d] = __builtin_amdgcn_mfma_f32_16x16x32_f16(ap, bv, ofr[d], 0, 0, 0);
            }
        }
    }
    #pragma unroll
    for (int r = 0; r < 4; ++r) {
        float v = lacc[r];
        v += __shfl_xor(v, 1, 64);
        v += __shfl_xor(v, 2, 64);
        v += __shfl_xor(v, 4, 64);
        v += __shfl_xor(v, 8, 64);
        lacc[r] = v;
    }
    #pragma unroll
    for (int r = 0; r < 4; ++r) {
        const float inv = 1.0f / lacc[r];
        float* orow = O + boff + (size_t)(qb + quad * 4 + r) * D_ + l15;
        #pragma unroll
        for (int d = 0; d < 4; ++d) orow[d * 16] = ofr[d][r] * inv;
    }
}

extern "C" void kernel_launch(void* const* d_in, const int* in_sizes, int n_in,
                              void* d_out, int out_size, void* d_ws, size_t ws_size,
                              hipStream_t stream) {
    const float* Q = (const float*)d_in[0];
    const float* K = (const float*)d_in[1];
    const float* V = (const float*)d_in[2];
    float* O = (float*)d_out;

    if (ws_size >= (size_t)8 * 1024 * 1024) {
        _Float16* K16  = (_Float16*)d_ws;                              // 2 MB
        _Float16* VT16 = K16 + (size_t)B_ * L_ * D_;                   // 2 MB
        prepass<<<768, NT, 0, stream>>>(K, V, K16, VT16);
        attn_hi<<<256, 1024, 0, stream>>>(Q, K16, VT16, O);
    } else {
        attn_mfma_f16<<<256, NT, 0, stream>>>(Q, K, V, O);
    }
}

// Round 13
// 85.077 us; speedup vs baseline: 1.3484x; 1.3484x over previous
//
#include <hip/hip_runtime.h>

// ScaledDotProductAttention B=8, L=2048, D=64, fp32 in/out.
//
// Two-launch scheme (ws >= 8 MB), R9 structure with FRAGMENT-MAJOR operands:
//  1) prepass_frag: writes K and V^T as MFMA fragments in the EXACT per-lane
//     order the attn waves consume:
//       K16F[((b*64+kt)*4 + s*2+c)*512 + lane*8]  (half8 = bk[s][c] of tile kt)
//       VT16F[((b*64+kt)*8 + d*2+ks)*256 + lane*4] (half4 = av[d][ks])
//     Hot-loop loads become fully coalesced sequential wave streams (~64
//     cache lines/wave-tile vs ~192 scattered partials with row-per-lane
//     addressing -- R7..R12 all shared that scatter; busy-% never rose with
//     occupancy => transaction path, not latency, is the suspected binder).
//     The scatter moves into the one-shot prepass (amortized 32x).
//  2) attn_qs4f: EXACT R9 structure (grid 256 = 8 batch x 32 qblocks of 64
//     queries, 4 waves, wave owns 512 keys = 16 tiles of 32; zero LDS / zero
//     cross-lane hot loop; S^T = K*Q^T 16x16x32; p=exp2 packed half4 == PV
//     B-frag; PV via mfma 16x16x16f16; R9 epilogue) -- only the two operand
//     address computations changed. Single-variable experiment.
// Fallback: proven R3 kernel if ws too small.

#define B_ 8
#define L_ 2048
#define D_ 64
#define NT 256

typedef _Float16 half8_t __attribute__((ext_vector_type(8)));
typedef _Float16 half4_t __attribute__((ext_vector_type(4)));
typedef float f32x4 __attribute__((ext_vector_type(4)));

#define SCALE_LOG2E 0.1803368801111244f   // 0.125 * log2(e)

// ------------------------------------------------------------ prepass_frag --
// blocks 0..511: K fragments for (b,kt); 512..1023: V^T fragments.
__global__ __launch_bounds__(NT) void prepass_frag(
    const float* __restrict__ K, const float* __restrict__ V,
    _Float16* __restrict__ K16F, _Float16* __restrict__ VT16F)
{
    const int blk = blockIdx.x;
    const int t = threadIdx.x;
    if (blk < 512) {
        const int b  = blk >> 6;
        const int kt = blk & 63;
        const int p    = t >> 6;          // plane = s*2 + c
        const int lane = t & 63;
        const int quad = lane >> 4;
        const int l15  = lane & 15;
        const int s = p >> 1, c = p & 1;
        const int row = kt * 32 + s * 16 + l15;
        const float* kp = K + ((size_t)b * L_ + row) * D_ + c * 32 + quad * 8;
        const float4 f0 = *(const float4*)kp;
        const float4 f1 = *(const float4*)(kp + 4);
        half8_t w;
        w[0] = (_Float16)f0.x; w[1] = (_Float16)f0.y;
        w[2] = (_Float16)f0.z; w[3] = (_Float16)f0.w;
        w[4] = (_Float16)f1.x; w[5] = (_Float16)f1.y;
        w[6] = (_Float16)f1.z; w[7] = (_Float16)f1.w;
        *(half8_t*)&K16F[((size_t)(b * 64 + kt) * 4 + p) * 512 + lane * 8] = w;
    } else {
        const int vb = blk - 512;
        const int b  = vb >> 6;
        const int kt = vb & 63;
        #pragma unroll
        for (int i = 0; i < 2; ++i) {
            const int slot = i * NT + t;      // 512 slots = 8 planes x 64 lanes
            const int p    = slot >> 6;       // plane = d*2 + ks
            const int lane = slot & 63;
            const int quad = lane >> 4;
            const int l15  = lane & 15;
            const int d = p >> 1, ks = p & 1;
            const int row = kt * 32 + ks * 16 + quad * 4;
            const int col = d * 16 + l15;
            const float* vp = V + ((size_t)b * L_ + row) * D_ + col;
            half4_t a;
            a[0] = (_Float16)vp[0];
            a[1] = (_Float16)vp[D_];
            a[2] = (_Float16)vp[2 * D_];
            a[3] = (_Float16)vp[3 * D_];
            *(half4_t*)&VT16F[((size_t)(b * 64 + kt) * 8 + p) * 256 + lane * 4] = a;
        }
    }
}

// -------------------------------------------------------------- main body --

// Load K B-frags of tile KT: one fully-coalesced half8/lane stream per plane.
#define LOADK(KT, BK)                                                           \
    {                                                                           \
        _Pragma("unroll") for (int s = 0; s < 2; ++s)                           \
        _Pragma("unroll") for (int c = 0; c < 2; ++c)                           \
            BK[s][c] = *(const half8_t*)&KbF[((size_t)(KT) * 4 + s * 2 + c) * 512 + lane * 8]; \
    }

// Process tile KT using pre-loaded K frags BK (R9 PROC, addresses changed).
#define PROC(KT, BK)                                                            \
    {                                                                           \
        half4_t av[4][2];                                                       \
        _Pragma("unroll") for (int d = 0; d < 4; ++d)                           \
        _Pragma("unroll") for (int ks = 0; ks < 2; ++ks)                        \
            av[d][ks] = *(const half4_t*)&VbF[((size_t)(KT) * 8 + d * 2 + ks) * 256 + lane * 4]; \
        f32x4 sc[2][4];                                                         \
        _Pragma("unroll") for (int ks = 0; ks < 2; ++ks)                        \
        _Pragma("unroll") for (int qs = 0; qs < 4; ++qs) {                      \
            f32x4 acc = (f32x4){0.f, 0.f, 0.f, 0.f};                            \
            acc = __builtin_amdgcn_mfma_f32_16x16x32_f16(BK[ks][0], bq[qs][0], acc, 0, 0, 0); \
            acc = __builtin_amdgcn_mfma_f32_16x16x32_f16(BK[ks][1], bq[qs][1], acc, 0, 0, 0); \
            sc[ks][qs] = acc;                                                   \
        }                                                                       \
        half4_t pb[2][4];                                                       \
        _Pragma("unroll") for (int ks = 0; ks < 2; ++ks)                        \
        _Pragma("unroll") for (int qs = 0; qs < 4; ++qs) {                      \
            const float p0 = __builtin_exp2f(sc[ks][qs][0]);                    \
            const float p1 = __builtin_exp2f(sc[ks][qs][1]);                    \
            const float p2 = __builtin_exp2f(sc[ks][qs][2]);                    \
            const float p3 = __builtin_exp2f(sc[ks][qs][3]);                    \
            lacc[qs] += (p0 + p1) + (p2 + p3);                                  \
            half4_t pv;                                                         \
            pv[0] = (_Float16)p0; pv[1] = (_Float16)p1;                         \
            pv[2] = (_Float16)p2; pv[3] = (_Float16)p3;                         \
            pb[ks][qs] = pv;                                                    \
        }                                                                       \
        _Pragma("unroll") for (int qs = 0; qs < 4; ++qs)                        \
        _Pragma("unroll") for (int d = 0; d < 4; ++d)                           \
        _Pragma("unroll") for (int ks = 0; ks < 2; ++ks)                        \
            ofr[qs][d] = __builtin_amdgcn_mfma_f32_16x16x16f16(av[d][ks], pb[ks][qs], ofr[qs][d], 0, 0, 0); \
    }

__global__ __launch_bounds__(NT) void attn_qs4f(
    const float* __restrict__ Q,
    const _Float16* __restrict__ K16F,
    const _Float16* __restrict__ VT16F,
    float* __restrict__ O)
{
    __shared__ float Ored[256 * 33];                     // 33792 B (epilogue only)
    __shared__ float Lred[256];                          // 1 KB

    const int t    = threadIdx.x;
    const int wave = t >> 6;
    const int lane = t & 63;
    const int quad = lane >> 4;
    const int l15  = lane & 15;

    const int b   = blockIdx.x & 7;            // batch <-> XCD affinity
    const int qbi = blockIdx.x >> 3;           // query block 0..31
    const int qb  = qbi * 64;
    const int kt0 = wave * 16;                 // wave's 16 tiles (512 keys)

    const _Float16* KbF = K16F + (size_t)b * 64 * 4 * 512;
    const _Float16* VbF = VT16F + (size_t)b * 64 * 8 * 256;

    // ---- Q B-frags from fp32, pre-scaled by 0.125*log2(e) ----
    half8_t bq[4][2];
    #pragma unroll
    for (int qs = 0; qs < 4; ++qs) {
        const float* qp = Q + ((size_t)b * L_ + qb + qs * 16 + l15) * D_ + quad * 8;
        #pragma unroll
        for (int c = 0; c < 2; ++c) {
            const float4 f0 = *(const float4*)(qp + c * 32);
            const float4 f1 = *(const float4*)(qp + c * 32 + 4);
            bq[qs][c][0] = (_Float16)(f0.x * SCALE_LOG2E);
            bq[qs][c][1] = (_Float16)(f0.y * SCALE_LOG2E);
            bq[qs][c][2] = (_Float16)(f0.z * SCALE_LOG2E);
            bq[qs][c][3] = (_Float16)(f0.w * SCALE_LOG2E);
            bq[qs][c][4] = (_Float16)(f1.x * SCALE_LOG2E);
            bq[qs][c][5] = (_Float16)(f1.y * SCALE_LOG2E);
            bq[qs][c][6] = (_Float16)(f1.z * SCALE_LOG2E);
            bq[qs][c][7] = (_Float16)(f1.w * SCALE_LOG2E);
        }
    }

    f32x4 ofr[4][4];
    #pragma unroll
    for (int qs = 0; qs < 4; ++qs)
        #pragma unroll
        for (int d = 0; d < 4; ++d)
            ofr[qs][d] = (f32x4){0.f, 0.f, 0.f, 0.f};
    float lacc[4] = {0.f, 0.f, 0.f, 0.f};

    // ---- hot loop: 16 tiles of 32 keys, K frags double-buffered ----
    half8_t bkA[2][2], bkB[2][2];
    LOADK(kt0, bkA);
    for (int it = 0; it < 8; ++it) {
        const int kta = kt0 + it * 2;
        LOADK(kta + 1, bkB);
        PROC(kta, bkA);
        // final prefetch overruns the wave's tile range; stays inside the ws
        // mapping (K16F is followed by VT16F) and is never consumed.
        LOADK(kta + 2, bkA);
        PROC(kta + 1, bkB);
    }

    // ---- l: reduce over quads (each lane holds 4 keys of query qs*16+l15) --
    #pragma unroll
    for (int qs = 0; qs < 4; ++qs) {
        float v = lacc[qs];
        v += __shfl_xor(v, 16, 64);
        v += __shfl_xor(v, 32, 64);
        lacc[qs] = v;
    }
    if (quad == 0) {
        #pragma unroll
        for (int qs = 0; qs < 4; ++qs)
            Lred[wave * 64 + qs * 16 + l15] = lacc[qs];
    }

    // ---- cross-wave combine, 2 passes over the shared buffer ----
    #pragma unroll
    for (int pass = 0; pass < 2; ++pass) {
        __syncthreads();
        #pragma unroll
        for (int qh = 0; qh < 2; ++qh) {
            const int qs = pass * 2 + qh;
            #pragma unroll
            for (int d = 0; d < 4; ++d)
                #pragma unroll
                for (int r = 0; r < 4; ++r)
                    Ored[(wave * 64 + lane) * 33 + qh * 16 + d * 4 + r] = ofr[qs][d][r];
        }
        __syncthreads();
        #pragma unroll
        for (int qh = 0; qh < 2; ++qh) {
            const int qs = pass * 2 + qh;
            const float lt = Lred[qs * 16 + l15] + Lred[64 + qs * 16 + l15]
                           + Lred[128 + qs * 16 + l15] + Lred[192 + qs * 16 + l15];
            const float inv = 1.0f / lt;
            f32x4 osum = (f32x4){0.f, 0.f, 0.f, 0.f};
            #pragma unroll
            for (int w2 = 0; w2 < 4; ++w2) {
                const float* src = &Ored[(w2 * 64 + lane) * 33 + qh * 16 + wave * 4];
                osum[0] += src[0]; osum[1] += src[1];
                osum[2] += src[2]; osum[3] += src[3];
            }
            float4 outv;
            outv.x = osum[0] * inv; outv.y = osum[1] * inv;
            outv.z = osum[2] * inv; outv.w = osum[3] * inv;
            // dim = wave*16 + quad*4 ; query = qb + qs*16 + l15
            *(float4*)&O[((size_t)b * L_ + qb + qs * 16 + l15) * D_ + wave * 16 + quad * 4] = outv;
        }
    }
}

// ------------------------------------------------- fallback (R3, no ws) --
#define KS 72
__global__ __launch_bounds__(NT) void attn_mfma_f16(
    const float* __restrict__ Q, const float* __restrict__ K,
    const float* __restrict__ V, float* __restrict__ O)
{
    __shared__ __align__(16) _Float16 Kt[64 * KS];
    __shared__ __align__(16) _Float16 Vt[D_ * KS];
    __shared__ __align__(16) _Float16 Pt[4][16 * KS];

    const int t = threadIdx.x;
    const int wave = t >> 6, lane = t & 63, quad = lane >> 4, l15 = lane & 15;
    const int bpb = L_ / 64;
    const int b = blockIdx.x / bpb;
    const int qb = (blockIdx.x % bpb) * 64 + wave * 16;
    const size_t boff = (size_t)b * L_ * D_;

    half8_t aq[2];
    {
        const float* qp = Q + boff + (size_t)(qb + l15) * D_ + quad * 8;
        #pragma unroll
        for (int c = 0; c < 2; ++c) {
            const float4* p4 = (const float4*)(qp + c * 32);
            const float4 f0 = p4[0], f1 = p4[1];
            aq[c][0] = (_Float16)f0.x; aq[c][1] = (_Float16)f0.y;
            aq[c][2] = (_Float16)f0.z; aq[c][3] = (_Float16)f0.w;
            aq[c][4] = (_Float16)f1.x; aq[c][5] = (_Float16)f1.y;
            aq[c][6] = (_Float16)f1.z; aq[c][7] = (_Float16)f1.w;
        }
    }
    f32x4 ofr[4];
    #pragma unroll
    for (int d = 0; d < 4; ++d) ofr[d] = (f32x4){0.f, 0.f, 0.f, 0.f};
    float lacc[4] = {0.f, 0.f, 0.f, 0.f};
    const int skey = t & 63, sdg = t >> 6;
    _Float16* Pw = &Pt[wave][0];

    for (int kt = 0; kt < L_ / 64; ++kt) {
        __syncthreads();
        {
            const float4* kg4 = (const float4*)(K + boff + (size_t)(kt * 64 + skey) * D_ + sdg * 16);
            const float4 f0 = kg4[0], f1 = kg4[1], f2 = kg4[2], f3 = kg4[3];
            half8_t w0, w1;
            w0[0] = (_Float16)f0.x; w0[1] = (_Float16)f0.y;
            w0[2] = (_Float16)f0.z; w0[3] = (_Float16)f0.w;
            w0[4] = (_Float16)f1.x; w0[5] = (_Float16)f1.y;
            w0[6] = (_Float16)f1.z; w0[7] = (_Float16)f1.w;
            w1[0] = (_Float16)f2.x; w1[1] = (_Float16)f2.y;
            w1[2] = (_Float16)f2.z; w1[3] = (_Float16)f2.w;
            w1[4] = (_Float16)f3.x; w1[5] = (_Float16)f3.y;
            w1[6] = (_Float16)f3.z; w1[7] = (_Float16)f3.w;
            *(half8_t*)&Kt[skey * KS + sdg * 16] = w0;
            *(half8_t*)&Kt[skey * KS + sdg * 16 + 8] = w1;
        }
        {
            const float4* vg4 = (const float4*)(V + boff + (size_t)(kt * 64 + skey) * D_ + sdg * 16);
            #pragma unroll
            for (int i = 0; i < 4; ++i) {
                const float4 f = vg4[i];
                const int d0 = sdg * 16 + i * 4;
                Vt[(d0 + 0) * KS + skey] = (_Float16)f.x;
                Vt[(d0 + 1) * KS + skey] = (_Float16)f.y;
                Vt[(d0 + 2) * KS + skey] = (_Float16)f.z;
                Vt[(d0 + 3) * KS + skey] = (_Float16)f.w;
            }
        }
        __syncthreads();
        #pragma unroll
        for (int s = 0; s < 4; ++s) {
            const half8_t bk0 = *(const half8_t*)&Kt[(s * 16 + l15) * KS + quad * 8];
            const half8_t bk1 = *(const half8_t*)&Kt[(s * 16 + l15) * KS + 32 + quad * 8];
            f32x4 sc = (f32x4){0.f, 0.f, 0.f, 0.f};
            sc = __builtin_amdgcn_mfma_f32_16x16x32_f16(aq[0], bk0, sc, 0, 0, 0);
            sc = __builtin_amdgcn_mfma_f32_16x16x32_f16(aq[1], bk1, sc, 0, 0, 0);
            #pragma unroll
            for (int r = 0; r < 4; ++r) {
                const float p = __expf(sc[r] * 0.125f);
                lacc[r] += p;
                Pw[(quad * 4 + r) * KS + s * 16 + l15] = (_Float16)p;
            }
        }
        __syncthreads();
        #pragma unroll
        for (int c = 0; c < 2; ++c) {
            const half8_t ap = *(const half8_t*)&Pw[l15 * KS + c * 32 + quad * 8];
            #pragma unroll
            for (int d = 0; d < 4; ++d) {
                const half8_t bv = *(const half8_t*)&Vt[(d * 16 + l15) * KS + c * 32 + quad * 8];
                ofr[d] = __builtin_amdgcn_mfma_f32_16x16x32_f16(ap, bv, ofr[d], 0, 0, 0);
            }
        }
    }
    #pragma unroll
    for (int r = 0; r < 4; ++r) {
        float v = lacc[r];
        v += __shfl_xor(v, 1, 64);
        v += __shfl_xor(v, 2, 64);
        v += __shfl_xor(v, 4, 64);
        v += __shfl_xor(v, 8, 64);
        lacc[r] = v;
    }
    #pragma unroll
    for (int r = 0; r < 4; ++r) {
        const float inv = 1.0f / lacc[r];
        float* orow = O + boff + (size_t)(qb + quad * 4 + r) * D_ + l15;
        #pragma unroll
        for (int d = 0; d < 4; ++d) orow[d * 16] = ofr[d][r] * inv;
    }
}

extern "C" void kernel_launch(void* const* d_in, const int* in_sizes, int n_in,
                              void* d_out, int out_size, void* d_ws, size_t ws_size,
                              hipStream_t stream) {
    const float* Q = (const float*)d_in[0];
    const float* K = (const float*)d_in[1];
    const float* V = (const float*)d_in[2];
    float* O = (float*)d_out;

    if (ws_size >= (size_t)8 * 1024 * 1024) {
        _Float16* K16F  = (_Float16*)d_ws;                             // 2 MB
        _Float16* VT16F = K16F + (size_t)1048576;                      // 2 MB
        prepass_frag<<<1024, NT, 0, stream>>>(K, V, K16F, VT16F);
        attn_qs4f<<<256, NT, 0, stream>>>(Q, K16F, VT16F, O);
    } else {
        attn_mfma_f16<<<256, NT, 0, stream>>>(Q, K, V, O);
    }
}

// Round 14
// 82.747 us; speedup vs baseline: 1.3864x; 1.0282x over previous
//
#include <hip/hip_runtime.h>

// ScaledDotProductAttention B=8, L=2048, D=64, fp32 in/out.
//
// Two-launch scheme (ws >= 8 MB). R13 (fragment-major operands, the verified
// ~7us win: kills the row-per-lane VMEM scatter) + TLP (this round):
//  1) prepass_frag: writes K and V^T as MFMA fragments in the EXACT per-lane
//     order the attn waves consume:
//       K16F[((b*64+kt)*4 + s*2+c)*512 + lane*8]  (half8 = bk[s][c] of tile kt)
//       VT16F[((b*64+kt)*8 + d*2+ks)*256 + lane*4] (half4 = av[d][ks])
//  2) attn_tlp: grid 512 = 8 batch x 64 qblocks of 32 queries; 512 threads =
//     8 waves -> 2 blocks/CU = 4 waves/SIMD (R13 ran 1 wave/SIMD; with the
//     transaction path fixed, exposed latency is the expected binder).
//     Wave owns keys [wave*256,+256) = 8 tiles of 32. Zero LDS / zero
//     cross-lane hot loop (R9-verified algebra):
//       - S^T = K*Q^T via mfma_f32_16x16x32_f16; lane holds
//         S^T[key=quad*4+r][q=qs*16+l15].
//       - p = exp2(s) (0.125*log2e folded into Q); packed half4 IS the
//         B-frag of mfma_f32_16x16x16f16 -> PV straight from registers.
//       - PV: O^T += VT16F half4 A-frags x P^T; float4-per-query store.
//     K/V frags per batch = 512 KB -> L2-resident per XCD (b = blockIdx&7).
//     Epilogue: 2 rounds over 36 KB LDS; 8-wave (O,l) combine (R10-verified).
// Fallback: proven R3 kernel if ws too small.

#define B_ 8
#define L_ 2048
#define D_ 64
#define NT 256

typedef _Float16 half8_t __attribute__((ext_vector_type(8)));
typedef _Float16 half4_t __attribute__((ext_vector_type(4)));
typedef float f32x4 __attribute__((ext_vector_type(4)));

#define SCALE_LOG2E 0.1803368801111244f   // 0.125 * log2(e)

// ------------------------------------------------------------ prepass_frag --
// blocks 0..511: K fragments for (b,kt); 512..1023: V^T fragments.
__global__ __launch_bounds__(NT) void prepass_frag(
    const float* __restrict__ K, const float* __restrict__ V,
    _Float16* __restrict__ K16F, _Float16* __restrict__ VT16F)
{
    const int blk = blockIdx.x;
    const int t = threadIdx.x;
    if (blk < 512) {
        const int b  = blk >> 6;
        const int kt = blk & 63;
        const int p    = t >> 6;          // plane = s*2 + c
        const int lane = t & 63;
        const int quad = lane >> 4;
        const int l15  = lane & 15;
        const int s = p >> 1, c = p & 1;
        const int row = kt * 32 + s * 16 + l15;
        const float* kp = K + ((size_t)b * L_ + row) * D_ + c * 32 + quad * 8;
        const float4 f0 = *(const float4*)kp;
        const float4 f1 = *(const float4*)(kp + 4);
        half8_t w;
        w[0] = (_Float16)f0.x; w[1] = (_Float16)f0.y;
        w[2] = (_Float16)f0.z; w[3] = (_Float16)f0.w;
        w[4] = (_Float16)f1.x; w[5] = (_Float16)f1.y;
        w[6] = (_Float16)f1.z; w[7] = (_Float16)f1.w;
        *(half8_t*)&K16F[((size_t)(b * 64 + kt) * 4 + p) * 512 + lane * 8] = w;
    } else {
        const int vb = blk - 512;
        const int b  = vb >> 6;
        const int kt = vb & 63;
        #pragma unroll
        for (int i = 0; i < 2; ++i) {
            const int slot = i * NT + t;      // 512 slots = 8 planes x 64 lanes
            const int p    = slot >> 6;       // plane = d*2 + ks
            const int lane = slot & 63;
            const int quad = lane >> 4;
            const int l15  = lane & 15;
            const int d = p >> 1, ks = p & 1;
            const int row = kt * 32 + ks * 16 + quad * 4;
            const int col = d * 16 + l15;
            const float* vp = V + ((size_t)b * L_ + row) * D_ + col;
            half4_t a;
            a[0] = (_Float16)vp[0];
            a[1] = (_Float16)vp[D_];
            a[2] = (_Float16)vp[2 * D_];
            a[3] = (_Float16)vp[3 * D_];
            *(half4_t*)&VT16F[((size_t)(b * 64 + kt) * 8 + p) * 256 + lane * 4] = a;
        }
    }
}

// -------------------------------------------------------------- main body --

// Load K B-frags of tile KT: one fully-coalesced half8/lane stream per plane.
#define LOADK(KT, BK)                                                           \
    {                                                                           \
        _Pragma("unroll") for (int s = 0; s < 2; ++s)                           \
        _Pragma("unroll") for (int c = 0; c < 2; ++c)                           \
            BK[s][c] = *(const half8_t*)&KbF[((size_t)(KT) * 4 + s * 2 + c) * 512 + lane * 8]; \
    }

// Process tile KT using pre-loaded K frags BK.
#define PROC(KT, BK)                                                            \
    {                                                                           \
        half4_t av[4][2];                                                       \
        _Pragma("unroll") for (int d = 0; d < 4; ++d)                           \
        _Pragma("unroll") for (int ks = 0; ks < 2; ++ks)                        \
            av[d][ks] = *(const half4_t*)&VbF[((size_t)(KT) * 8 + d * 2 + ks) * 256 + lane * 4]; \
        f32x4 sc[2][2];                                                         \
        _Pragma("unroll") for (int ks = 0; ks < 2; ++ks)                        \
        _Pragma("unroll") for (int qs = 0; qs < 2; ++qs) {                      \
            f32x4 acc = (f32x4){0.f, 0.f, 0.f, 0.f};                            \
            acc = __builtin_amdgcn_mfma_f32_16x16x32_f16(BK[ks][0], bq[qs][0], acc, 0, 0, 0); \
            acc = __builtin_amdgcn_mfma_f32_16x16x32_f16(BK[ks][1], bq[qs][1], acc, 0, 0, 0); \
            sc[ks][qs] = acc;                                                   \
        }                                                                       \
        half4_t pb[2][2];                                                       \
        _Pragma("unroll") for (int ks = 0; ks < 2; ++ks)                        \
        _Pragma("unroll") for (int qs = 0; qs < 2; ++qs) {                      \
            const float p0 = __builtin_exp2f(sc[ks][qs][0]);                    \
            const float p1 = __builtin_exp2f(sc[ks][qs][1]);                    \
            const float p2 = __builtin_exp2f(sc[ks][qs][2]);                    \
            const float p3 = __builtin_exp2f(sc[ks][qs][3]);                    \
            lacc[qs] += (p0 + p1) + (p2 + p3);                                  \
            half4_t pv;                                                         \
            pv[0] = (_Float16)p0; pv[1] = (_Float16)p1;                         \
            pv[2] = (_Float16)p2; pv[3] = (_Float16)p3;                         \
            pb[ks][qs] = pv;                                                    \
        }                                                                       \
        _Pragma("unroll") for (int qs = 0; qs < 2; ++qs)                        \
        _Pragma("unroll") for (int d = 0; d < 4; ++d)                           \
        _Pragma("unroll") for (int ks = 0; ks < 2; ++ks)                        \
            ofr[qs][d] = __builtin_amdgcn_mfma_f32_16x16x16f16(av[d][ks], pb[ks][qs], ofr[qs][d], 0, 0, 0); \
    }

__global__ __launch_bounds__(512, 4) void attn_tlp(
    const float* __restrict__ Q,
    const _Float16* __restrict__ K16F,
    const _Float16* __restrict__ VT16F,
    float* __restrict__ O)
{
    __shared__ float Ored[512 * 17];                     // 34816 B (epilogue only)
    __shared__ float Lred[256];                          // 1 KB

    const int t    = threadIdx.x;
    const int wave = t >> 6;                   // 0..7 (key-range owner)
    const int lane = t & 63;
    const int quad = lane >> 4;
    const int l15  = lane & 15;

    const int b   = blockIdx.x & 7;            // batch <-> XCD affinity
    const int qbi = blockIdx.x >> 3;           // query block 0..63
    const int qb  = qbi * 32;
    const int kt0 = wave * 8;                  // wave's 8 tiles (256 keys)

    const _Float16* KbF = K16F + (size_t)b * 64 * 4 * 512;
    const _Float16* VbF = VT16F + (size_t)b * 64 * 8 * 256;

    // ---- Q B-frags from fp32, pre-scaled by 0.125*log2(e) ----
    half8_t bq[2][2];
    #pragma unroll
    for (int qs = 0; qs < 2; ++qs) {
        const float* qp = Q + ((size_t)b * L_ + qb + qs * 16 + l15) * D_ + quad * 8;
        #pragma unroll
        for (int c = 0; c < 2; ++c) {
            const float4 f0 = *(const float4*)(qp + c * 32);
            const float4 f1 = *(const float4*)(qp + c * 32 + 4);
            bq[qs][c][0] = (_Float16)(f0.x * SCALE_LOG2E);
            bq[qs][c][1] = (_Float16)(f0.y * SCALE_LOG2E);
            bq[qs][c][2] = (_Float16)(f0.z * SCALE_LOG2E);
            bq[qs][c][3] = (_Float16)(f0.w * SCALE_LOG2E);
            bq[qs][c][4] = (_Float16)(f1.x * SCALE_LOG2E);
            bq[qs][c][5] = (_Float16)(f1.y * SCALE_LOG2E);
            bq[qs][c][6] = (_Float16)(f1.z * SCALE_LOG2E);
            bq[qs][c][7] = (_Float16)(f1.w * SCALE_LOG2E);
        }
    }

    f32x4 ofr[2][4];
    #pragma unroll
    for (int qs = 0; qs < 2; ++qs)
        #pragma unroll
        for (int d = 0; d < 4; ++d)
            ofr[qs][d] = (f32x4){0.f, 0.f, 0.f, 0.f};
    float lacc[2] = {0.f, 0.f};

    // ---- hot loop: 8 tiles of 32 keys, K frags double-buffered ----
    half8_t bkA[2][2], bkB[2][2];
    LOADK(kt0, bkA);
    for (int it = 0; it < 4; ++it) {
        const int kta = kt0 + it * 2;
        LOADK(kta + 1, bkB);
        PROC(kta, bkA);
        // final prefetch overruns the wave's tile range; stays inside the ws
        // mapping (K16F is followed by VT16F) and is never consumed.
        LOADK(kta + 2, bkA);
        PROC(kta + 1, bkB);
    }

    // ---- l: reduce over quads (each lane holds 4 keys of query qs*16+l15) --
    #pragma unroll
    for (int qs = 0; qs < 2; ++qs) {
        float v = lacc[qs];
        v += __shfl_xor(v, 16, 64);
        v += __shfl_xor(v, 32, 64);
        lacc[qs] = v;
    }
    if (quad == 0) {
        Lred[wave * 32 + l15] = lacc[0];
        Lred[wave * 32 + 16 + l15] = lacc[1];
    }

    // ---- cross-wave combine: 2 rounds (one qs each) over shared buffer ----
    #pragma unroll
    for (int qs = 0; qs < 2; ++qs) {
        __syncthreads();   // previous round's reads (and Lred writes) done
        #pragma unroll
        for (int d = 0; d < 4; ++d)
            #pragma unroll
            for (int r = 0; r < 4; ++r)
                Ored[(wave * 64 + lane) * 17 + d * 4 + r] = ofr[qs][d][r];
        __syncthreads();
        if (wave < 4) {
            float lt = 0.f;
            #pragma unroll
            for (int w2 = 0; w2 < 8; ++w2)
                lt += Lred[w2 * 32 + qs * 16 + l15];
            const float inv = 1.0f / lt;
            f32x4 osum = (f32x4){0.f, 0.f, 0.f, 0.f};
            #pragma unroll
            for (int w2 = 0; w2 < 8; ++w2) {
                const float* src = &Ored[(w2 * 64 + lane) * 17 + wave * 4];
                osum[0] += src[0]; osum[1] += src[1];
                osum[2] += src[2]; osum[3] += src[3];
            }
            float4 outv;
            outv.x = osum[0] * inv; outv.y = osum[1] * inv;
            outv.z = osum[2] * inv; outv.w = osum[3] * inv;
            // query = qb + qs*16 + l15 ; dims = wave*16 + quad*4 .. +4
            *(float4*)&O[((size_t)b * L_ + qb + qs * 16 + l15) * D_ + wave * 16 + quad * 4] = outv;
        }
    }
}

// ------------------------------------------------- fallback (R3, no ws) --
#define KS 72
__global__ __launch_bounds__(NT) void attn_mfma_f16(
    const float* __restrict__ Q, const float* __restrict__ K,
    const float* __restrict__ V, float* __restrict__ O)
{
    __shared__ __align__(16) _Float16 Kt[64 * KS];
    __shared__ __align__(16) _Float16 Vt[D_ * KS];
    __shared__ __align__(16) _Float16 Pt[4][16 * KS];

    const int t = threadIdx.x;
    const int wave = t >> 6, lane = t & 63, quad = lane >> 4, l15 = lane & 15;
    const int bpb = L_ / 64;
    const int b = blockIdx.x / bpb;
    const int qb = (blockIdx.x % bpb) * 64 + wave * 16;
    const size_t boff = (size_t)b * L_ * D_;

    half8_t aq[2];
    {
        const float* qp = Q + boff + (size_t)(qb + l15) * D_ + quad * 8;
        #pragma unroll
        for (int c = 0; c < 2; ++c) {
            const float4* p4 = (const float4*)(qp + c * 32);
            const float4 f0 = p4[0], f1 = p4[1];
            aq[c][0] = (_Float16)f0.x; aq[c][1] = (_Float16)f0.y;
            aq[c][2] = (_Float16)f0.z; aq[c][3] = (_Float16)f0.w;
            aq[c][4] = (_Float16)f1.x; aq[c][5] = (_Float16)f1.y;
            aq[c][6] = (_Float16)f1.z; aq[c][7] = (_Float16)f1.w;
        }
    }
    f32x4 ofr[4];
    #pragma unroll
    for (int d = 0; d < 4; ++d) ofr[d] = (f32x4){0.f, 0.f, 0.f, 0.f};
    float lacc[4] = {0.f, 0.f, 0.f, 0.f};
    const int skey = t & 63, sdg = t >> 6;
    _Float16* Pw = &Pt[wave][0];

    for (int kt = 0; kt < L_ / 64; ++kt) {
        __syncthreads();
        {
            const float4* kg4 = (const float4*)(K + boff + (size_t)(kt * 64 + skey) * D_ + sdg * 16);
            const float4 f0 = kg4[0], f1 = kg4[1], f2 = kg4[2], f3 = kg4[3];
            half8_t w0, w1;
            w0[0] = (_Float16)f0.x; w0[1] = (_Float16)f0.y;
            w0[2] = (_Float16)f0.z; w0[3] = (_Float16)f0.w;
            w0[4] = (_Float16)f1.x; w0[5] = (_Float16)f1.y;
            w0[6] = (_Float16)f1.z; w0[7] = (_Float16)f1.w;
            w1[0] = (_Float16)f2.x; w1[1] = (_Float16)f2.y;
            w1[2] = (_Float16)f2.z; w1[3] = (_Float16)f2.w;
            w1[4] = (_Float16)f3.x; w1[5] = (_Float16)f3.y;
            w1[6] = (_Float16)f3.z; w1[7] = (_Float16)f3.w;
            *(half8_t*)&Kt[skey * KS + sdg * 16] = w0;
            *(half8_t*)&Kt[skey * KS + sdg * 16 + 8] = w1;
        }
        {
            const float4* vg4 = (const float4*)(V + boff + (size_t)(kt * 64 + skey) * D_ + sdg * 16);
            #pragma unroll
            for (int i = 0; i < 4; ++i) {
                const float4 f = vg4[i];
                const int d0 = sdg * 16 + i * 4;
                Vt[(d0 + 0) * KS + skey] = (_Float16)f.x;
                Vt[(d0 + 1) * KS + skey] = (_Float16)f.y;
                Vt[(d0 + 2) * KS + skey] = (_Float16)f.z;
                Vt[(d0 + 3) * KS + skey] = (_Float16)f.w;
            }
        }
        __syncthreads();
        #pragma unroll
        for (int s = 0; s < 4; ++s) {
            const half8_t bk0 = *(const half8_t*)&Kt[(s * 16 + l15) * KS + quad * 8];
            const half8_t bk1 = *(const half8_t*)&Kt[(s * 16 + l15) * KS + 32 + quad * 8];
            f32x4 sc = (f32x4){0.f, 0.f, 0.f, 0.f};
            sc = __builtin_amdgcn_mfma_f32_16x16x32_f16(aq[0], bk0, sc, 0, 0, 0);
            sc = __builtin_amdgcn_mfma_f32_16x16x32_f16(aq[1], bk1, sc, 0, 0, 0);
            #pragma unroll
            for (int r = 0; r < 4; ++r) {
                const float p = __expf(sc[r] * 0.125f);
                lacc[r] += p;
                Pw[(quad * 4 + r) * KS + s * 16 + l15] = (_Float16)p;
            }
        }
        __syncthreads();
        #pragma unroll
        for (int c = 0; c < 2; ++c) {
            const half8_t ap = *(const half8_t*)&Pw[l15 * KS + c * 32 + quad * 8];
            #pragma unroll
            for (int d = 0; d < 4; ++d) {
                const half8_t bv = *(const half8_t*)&Vt[(d * 16 + l15) * KS + c * 32 + quad * 8];
                ofr[d] = __builtin_amdgcn_mfma_f32_16x16x32_f16(ap, bv, ofr[d], 0, 0, 0);
            }
        }
    }
    #pragma unroll
    for (int r = 0; r < 4; ++r) {
        float v = lacc[r];
        v += __shfl_xor(v, 1, 64);
        v += __shfl_xor(v, 2, 64);
        v += __shfl_xor(v, 4, 64);
        v += __shfl_xor(v, 8, 64);
        lacc[r] = v;
    }
    #pragma unroll
    for (int r = 0; r < 4; ++r) {
        const float inv = 1.0f / lacc[r];
        float* orow = O + boff + (size_t)(qb + quad * 4 + r) * D_ + l15;
        #pragma unroll
        for (int d = 0; d < 4; ++d) orow[d * 16] = ofr[d][r] * inv;
    }
}

extern "C" void kernel_launch(void* const* d_in, const int* in_sizes, int n_in,
                              void* d_out, int out_size, void* d_ws, size_t ws_size,
                              hipStream_t stream) {
    const float* Q = (const float*)d_in[0];
    const float* K = (const float*)d_in[1];
    const float* V = (const float*)d_in[2];
    float* O = (float*)d_out;

    if (ws_size >= (size_t)8 * 1024 * 1024) {
        _Float16* K16F  = (_Float16*)d_ws;                             // 2 MB
        _Float16* VT16F = K16F + (size_t)1048576;                      // 2 MB
        prepass_frag<<<1024, NT, 0, stream>>>(K, V, K16F, VT16F);
        attn_tlp<<<512, 512, 0, stream>>>(Q, K16F, VT16F, O);
    } else {
        attn_mfma_f16<<<256, NT, 0, stream>>>(Q, K, V, O);
    }
}